// Round 14
// baseline (119.738 us; speedup 1.0000x reference)
//
#include <hip/hip_runtime.h>
#include <math.h>

#define FEAT 128
#define FXS 16777216.0f          // 2^24 fixed-point scale for edge weights
#define FXI (1.0f / 16777216.0f)
#define AGG_BLOCKS 2048          // k_agg grid; also BN partial rows
#define NPB 256                  // nodes per bucket (bucket = c >> 8)
#define EPBA 4096                // edges per phase-A block

typedef __attribute__((ext_vector_type(8)))  short short8;
typedef __attribute__((ext_vector_type(16))) float f32x16;

// bf16 helpers (bit-level, RNE pack / exact unpack)
__device__ inline unsigned pkbf(float a, float b) {
    unsigned ua = __float_as_uint(a), ub = __float_as_uint(b);
    ua += 0x7fffu + ((ua >> 16) & 1u);
    ub += 0x7fffu + ((ub >> 16) & 1u);
    return (ua >> 16) | (ub & 0xffff0000u);
}
__device__ inline unsigned short bf16of(float a) {
    unsigned ua = __float_as_uint(a);
    ua += 0x7fffu + ((ua >> 16) & 1u);
    return (unsigned short)(ua >> 16);
}
__device__ inline float2 upbf(unsigned v) {
    return make_float2(__uint_as_float(v << 16), __uint_as_float(v & 0xffff0000u));
}

// ---------------------------------------------------------------------------
// Kernel A: init — bucket cursors, BN sums, done counter, start[n]=E
// ---------------------------------------------------------------------------
__global__ __launch_bounds__(256) void k_init2(unsigned* __restrict__ gcur,
                                               float* __restrict__ bnsum, float* __restrict__ bnsq,
                                               int* __restrict__ start, unsigned* __restrict__ done,
                                               int nbuk, int cap, int n, int E) {
    int i = threadIdx.x;
    if (i < nbuk) gcur[i] = (unsigned)(i * cap);
    if (i < FEAT) { bnsum[i] = 0.0f; bnsq[i] = 0.0f; }
    if (i == 0) { start[n] = E; *done = 0u; }
}

// ---------------------------------------------------------------------------
// Kernel B (phase A): bucket-partition edges.
// Record: u64 = r | c<<17 | fx24(ew)<<34
// ---------------------------------------------------------------------------
__global__ __launch_bounds__(256) void k_bucket(const int* __restrict__ ei, const float* __restrict__ ew,
                                                unsigned long long* __restrict__ buk,
                                                unsigned* __restrict__ gcur,
                                                int E, int nbuk, int cap) {
    __shared__ unsigned bcnt[256];
    __shared__ unsigned bbase[256];
    const int tid = threadIdx.x;
    for (int i = tid; i < nbuk; i += 256) bcnt[i] = 0;
    __syncthreads();
    const int e0 = blockIdx.x * EPBA;
    const int e1 = (e0 + EPBA < E) ? e0 + EPBA : E;
    for (int e = e0 + tid; e < e1; e += 256) {
        int c = ei[E + e];
        atomicAdd(&bcnt[c >> 8], 1u);
    }
    __syncthreads();
    for (int i = tid; i < nbuk; i += 256) {
        unsigned nn = bcnt[i];
        bbase[i] = nn ? atomicAdd(&gcur[i], nn) : 0u;
        bcnt[i] = 0;   // reuse as local cursor
    }
    __syncthreads();
    for (int e = e0 + tid; e < e1; e += 256) {
        int r = ei[e];
        int c = ei[E + e];
        unsigned fx = (unsigned)(ew[e] * FXS + 0.5f);
        int b = c >> 8;
        unsigned slot = bbase[b] + atomicAdd(&bcnt[b], 1u);
        buk[slot] = (unsigned long long)(unsigned)r
                  | ((unsigned long long)(unsigned)c << 17)
                  | ((unsigned long long)fx << 34);
    }
}

// ---------------------------------------------------------------------------
// Kernel C (phase B): per-bucket CSR build. One block per bucket.
// ---------------------------------------------------------------------------
__global__ __launch_bounds__(256) void k_csr(const unsigned long long* __restrict__ buk,
                                             const unsigned* __restrict__ gcur,
                                             int2* __restrict__ rec, int* __restrict__ start,
                                             float* __restrict__ dinv,
                                             int n, int nbuk, int cap) {
    __shared__ unsigned long long cd[NPB];
    __shared__ unsigned curL[NPB];
    __shared__ unsigned sizeL[256];
    __shared__ unsigned wt[4];
    const int b = blockIdx.x;
    const int tid = threadIdx.x;
    const int lane = tid & 63;
    const int wv = tid >> 6;

    unsigned sz = (tid < nbuk) ? (gcur[tid] - (unsigned)(tid * cap)) : 0u;
    {
        unsigned s = sz;
#pragma unroll
        for (int o = 1; o < 64; o <<= 1) {
            unsigned u = __shfl_up((int)s, o);
            if (lane >= o) s += u;
        }
        if (lane == 63) wt[wv] = s;
        __syncthreads();
        unsigned woff = 0;
#pragma unroll
        for (int w = 0; w < 4; w++) if (w < wv) woff += wt[w];
        sizeL[tid] = woff + s - sz;   // exclusive
        __syncthreads();
    }
    const unsigned bukStartG = sizeL[b];
    const unsigned mySize = gcur[b] - (unsigned)(b * cap);
    const unsigned base = (unsigned)b * (unsigned)cap;

    cd[tid] = 0ULL;
    __syncthreads();

    for (unsigned i = tid; i < mySize; i += 256) {
        unsigned long long v = buk[base + i];
        unsigned ci = ((unsigned)(v >> 17)) & 255u;
        atomicAdd(&cd[ci], (1ULL << 40) | (v >> 34));
    }
    __syncthreads();

    {
        unsigned long long v = cd[tid];
        unsigned cnt = (unsigned)(v >> 40);
        float deg = 1.0f + (float)(v & ((1ULL << 40) - 1ULL)) * FXI;
        unsigned s = cnt;
#pragma unroll
        for (int o = 1; o < 64; o <<= 1) {
            unsigned u = __shfl_up((int)s, o);
            if (lane >= o) s += u;
        }
        __syncthreads();          // wt reuse
        if (lane == 63) wt[wv] = s;
        __syncthreads();
        unsigned woff = 0;
#pragma unroll
        for (int w = 0; w < 4; w++) if (w < wv) woff += wt[w];
        unsigned excl = woff + s - cnt;
        curL[tid] = bukStartG + excl;
        int gc = b * NPB + tid;
        if (gc < n) {
            start[gc] = (int)(bukStartG + excl);
            dinv[gc] = rsqrtf(deg);
        }
    }
    __syncthreads();

    for (unsigned i = tid; i < mySize; i += 256) {
        unsigned long long v = buk[base + i];
        unsigned r = (unsigned)v & 0x1FFFFu;
        unsigned ci = ((unsigned)(v >> 17)) & 255u;
        float w = (float)(v >> 34) * FXI;
        unsigned pos = atomicAdd(&curL[ci], 1u);
        rec[pos] = make_int2((int)r, __float_as_int(w));
    }
}

// ---------------------------------------------------------------------------
// Kernel F: hbs = (x @ W) * dinv[row]  via MFMA 32x32x16 bf16
// ---------------------------------------------------------------------------
__global__ __launch_bounds__(256) void k_gemm_mfma(const float* __restrict__ x,
                                                   const float* __restrict__ Wg,
                                                   const float* __restrict__ dinv,
                                                   unsigned short* __restrict__ hb, int nrows) {
    __shared__ unsigned wlds[4][8][64][4];   // 32 KB
    const int tid = threadIdx.x;

    for (int idx = tid; idx < 4 * 8 * 64; idx += 256) {
        int lane = idx & 63;
        int ks = (idx >> 6) & 7;
        int ct = idx >> 9;
        int krow = ks * 16 + 8 * (lane >> 5);
        int col = ct * 32 + (lane & 31);
        unsigned u0 = pkbf(Wg[(krow + 0) * FEAT + col], Wg[(krow + 1) * FEAT + col]);
        unsigned u1 = pkbf(Wg[(krow + 2) * FEAT + col], Wg[(krow + 3) * FEAT + col]);
        unsigned u2 = pkbf(Wg[(krow + 4) * FEAT + col], Wg[(krow + 5) * FEAT + col]);
        unsigned u3 = pkbf(Wg[(krow + 6) * FEAT + col], Wg[(krow + 7) * FEAT + col]);
        *(uint4*)&wlds[ct][ks][lane][0] = make_uint4(u0, u1, u2, u3);
    }
    __syncthreads();

    const int w = tid >> 6;
    const int lane = tid & 63;
    const int row = blockIdx.x * 128 + w * 32 + (lane & 31);
    const int rclamp = (row < nrows) ? row : 0;
    const float* xrow = x + (size_t)rclamp * FEAT + 8 * (lane >> 5);

    f32x16 acc0 = {0}, acc1 = {0}, acc2 = {0}, acc3 = {0};

#pragma unroll
    for (int ks = 0; ks < 8; ks++) {
        float4 f0 = *(const float4*)&xrow[ks * 16];
        float4 f1 = *(const float4*)&xrow[ks * 16 + 4];
        union { uint4 u; short8 s; } a;
        a.u = make_uint4(pkbf(f0.x, f0.y), pkbf(f0.z, f0.w), pkbf(f1.x, f1.y), pkbf(f1.z, f1.w));
        union { uint4 u; short8 s; } b0, b1, b2, b3;
        b0.u = *(const uint4*)&wlds[0][ks][lane][0];
        b1.u = *(const uint4*)&wlds[1][ks][lane][0];
        b2.u = *(const uint4*)&wlds[2][ks][lane][0];
        b3.u = *(const uint4*)&wlds[3][ks][lane][0];
        acc0 = __builtin_amdgcn_mfma_f32_32x32x16_bf16(a.s, b0.s, acc0, 0, 0, 0);
        acc1 = __builtin_amdgcn_mfma_f32_32x32x16_bf16(a.s, b1.s, acc1, 0, 0, 0);
        acc2 = __builtin_amdgcn_mfma_f32_32x32x16_bf16(a.s, b2.s, acc2, 0, 0, 0);
        acc3 = __builtin_amdgcn_mfma_f32_32x32x16_bf16(a.s, b3.s, acc3, 0, 0, 0);
    }

    const int rb = blockIdx.x * 128 + w * 32 + 4 * (lane >> 5);
    const int cb = lane & 31;
#pragma unroll
    for (int r = 0; r < 16; r++) {
        int rr = rb + (r & 3) + 8 * (r >> 2);
        if (rr < nrows) {
            float dv = dinv[rr];
            unsigned short* p = hb + (size_t)rr * FEAT + cb;
            p[0]  = bf16of(acc0[r] * dv);
            p[32] = bf16of(acc1[r] * dv);
            p[64] = bf16of(acc2[r] * dv);
            p[96] = bf16of(acc3[r] * dv);
        }
    }
}

// ---------------------------------------------------------------------------
// Kernel G: aggregate + fused BN partials (R12 structure, 16-deep main loop:
// 8 uint4 rec loads + 16 row-gathers in flight before consumption).
// ---------------------------------------------------------------------------
__global__ __launch_bounds__(256) void k_agg(const int* __restrict__ start,
                                             const int2* __restrict__ rec, const float* __restrict__ dinv,
                                             const unsigned* __restrict__ hb, const float* __restrict__ b,
                                             unsigned* __restrict__ obf,
                                             float* __restrict__ ps, float* __restrict__ pss, int n) {
    const int tid = threadIdx.x;
    const int lane = tid & 63;
    const int wv = tid >> 6;
    const int j0 = lane * 2;
    const float bx = b[j0];
    const float by = b[j0 + 1];

    float sx = 0.0f, ssx = 0.0f, sy = 0.0f, ssy = 0.0f;

    for (int c = blockIdx.x * 4 + wv; c < n; c += AGG_BLOCKS * 4) {
        const int s0 = start[c];
        const int m = start[c + 1] - s0;
        const float dc = dinv[c];

        float2 hv = upbf(hb[(size_t)c * 64 + lane]);
        float ax = hv.x * dc + bx;
        float ay = hv.y * dc + by;

        int k = 0;
        for (; k + 15 < m; k += 16) {
            uint4 r0 = *(const uint4*)&rec[s0 + k];
            uint4 r1 = *(const uint4*)&rec[s0 + k + 2];
            uint4 r2 = *(const uint4*)&rec[s0 + k + 4];
            uint4 r3 = *(const uint4*)&rec[s0 + k + 6];
            uint4 r4 = *(const uint4*)&rec[s0 + k + 8];
            uint4 r5 = *(const uint4*)&rec[s0 + k + 10];
            uint4 r6 = *(const uint4*)&rec[s0 + k + 12];
            uint4 r7 = *(const uint4*)&rec[s0 + k + 14];
            unsigned g0 = hb[(size_t)r0.x * 64 + lane];
            unsigned g1 = hb[(size_t)r0.z * 64 + lane];
            unsigned g2 = hb[(size_t)r1.x * 64 + lane];
            unsigned g3 = hb[(size_t)r1.z * 64 + lane];
            unsigned g4 = hb[(size_t)r2.x * 64 + lane];
            unsigned g5 = hb[(size_t)r2.z * 64 + lane];
            unsigned g6 = hb[(size_t)r3.x * 64 + lane];
            unsigned g7 = hb[(size_t)r3.z * 64 + lane];
            unsigned g8 = hb[(size_t)r4.x * 64 + lane];
            unsigned g9 = hb[(size_t)r4.z * 64 + lane];
            unsigned gA = hb[(size_t)r5.x * 64 + lane];
            unsigned gB = hb[(size_t)r5.z * 64 + lane];
            unsigned gC = hb[(size_t)r6.x * 64 + lane];
            unsigned gD = hb[(size_t)r6.z * 64 + lane];
            unsigned gE = hb[(size_t)r7.x * 64 + lane];
            unsigned gF = hb[(size_t)r7.z * 64 + lane];
            float w0 = __uint_as_float(r0.y) * dc, w1 = __uint_as_float(r0.w) * dc;
            float w2 = __uint_as_float(r1.y) * dc, w3 = __uint_as_float(r1.w) * dc;
            float w4 = __uint_as_float(r2.y) * dc, w5 = __uint_as_float(r2.w) * dc;
            float w6 = __uint_as_float(r3.y) * dc, w7 = __uint_as_float(r3.w) * dc;
            float w8 = __uint_as_float(r4.y) * dc, w9 = __uint_as_float(r4.w) * dc;
            float wA = __uint_as_float(r5.y) * dc, wB = __uint_as_float(r5.w) * dc;
            float wC = __uint_as_float(r6.y) * dc, wD = __uint_as_float(r6.w) * dc;
            float wE = __uint_as_float(r7.y) * dc, wF = __uint_as_float(r7.w) * dc;
            float2 v0 = upbf(g0), v1 = upbf(g1), v2 = upbf(g2), v3 = upbf(g3);
            float2 v4 = upbf(g4), v5 = upbf(g5), v6 = upbf(g6), v7 = upbf(g7);
            float2 v8 = upbf(g8), v9 = upbf(g9), vA = upbf(gA), vB = upbf(gB);
            float2 vC = upbf(gC), vD = upbf(gD), vE = upbf(gE), vF = upbf(gF);
            ax += v0.x * w0 + v1.x * w1 + v2.x * w2 + v3.x * w3
                + v4.x * w4 + v5.x * w5 + v6.x * w6 + v7.x * w7
                + v8.x * w8 + v9.x * w9 + vA.x * wA + vB.x * wB
                + vC.x * wC + vD.x * wD + vE.x * wE + vF.x * wF;
            ay += v0.y * w0 + v1.y * w1 + v2.y * w2 + v3.y * w3
                + v4.y * w4 + v5.y * w5 + v6.y * w6 + v7.y * w7
                + v8.y * w8 + v9.y * w9 + vA.y * wA + vB.y * wB
                + vC.y * wC + vD.y * wD + vE.y * wE + vF.y * wF;
        }
        for (; k + 7 < m; k += 8) {
            uint4 ra = *(const uint4*)&rec[s0 + k];
            uint4 rb2 = *(const uint4*)&rec[s0 + k + 2];
            uint4 rc = *(const uint4*)&rec[s0 + k + 4];
            uint4 rd = *(const uint4*)&rec[s0 + k + 6];
            unsigned g0 = hb[(size_t)ra.x  * 64 + lane];
            unsigned g1 = hb[(size_t)ra.z  * 64 + lane];
            unsigned g2 = hb[(size_t)rb2.x * 64 + lane];
            unsigned g3 = hb[(size_t)rb2.z * 64 + lane];
            unsigned g4 = hb[(size_t)rc.x  * 64 + lane];
            unsigned g5 = hb[(size_t)rc.z  * 64 + lane];
            unsigned g6 = hb[(size_t)rd.x  * 64 + lane];
            unsigned g7 = hb[(size_t)rd.z  * 64 + lane];
            float w0 = __uint_as_float(ra.y)  * dc;
            float w1 = __uint_as_float(ra.w)  * dc;
            float w2 = __uint_as_float(rb2.y) * dc;
            float w3 = __uint_as_float(rb2.w) * dc;
            float w4 = __uint_as_float(rc.y)  * dc;
            float w5 = __uint_as_float(rc.w)  * dc;
            float w6 = __uint_as_float(rd.y)  * dc;
            float w7 = __uint_as_float(rd.w)  * dc;
            float2 v0 = upbf(g0), v1 = upbf(g1), v2 = upbf(g2), v3 = upbf(g3);
            float2 v4 = upbf(g4), v5 = upbf(g5), v6 = upbf(g6), v7 = upbf(g7);
            ax += v0.x * w0 + v1.x * w1 + v2.x * w2 + v3.x * w3
                + v4.x * w4 + v5.x * w5 + v6.x * w6 + v7.x * w7;
            ay += v0.y * w0 + v1.y * w1 + v2.y * w2 + v3.y * w3
                + v4.y * w4 + v5.y * w5 + v6.y * w6 + v7.y * w7;
        }
        for (; k + 3 < m; k += 4) {
            uint4 ra = *(const uint4*)&rec[s0 + k];
            uint4 rb2 = *(const uint4*)&rec[s0 + k + 2];
            unsigned g0 = hb[(size_t)ra.x  * 64 + lane];
            unsigned g1 = hb[(size_t)ra.z  * 64 + lane];
            unsigned g2 = hb[(size_t)rb2.x * 64 + lane];
            unsigned g3 = hb[(size_t)rb2.z * 64 + lane];
            float w0 = __uint_as_float(ra.y)  * dc;
            float w1 = __uint_as_float(ra.w)  * dc;
            float w2 = __uint_as_float(rb2.y) * dc;
            float w3 = __uint_as_float(rb2.w) * dc;
            float2 v0 = upbf(g0), v1 = upbf(g1), v2 = upbf(g2), v3 = upbf(g3);
            ax += v0.x * w0 + v1.x * w1 + v2.x * w2 + v3.x * w3;
            ay += v0.y * w0 + v1.y * w1 + v2.y * w2 + v3.y * w3;
        }
        for (; k < m; k++) {
            int2 r0 = rec[s0 + k];
            float w = __int_as_float(r0.y) * dc;
            float2 v = upbf(hb[(size_t)r0.x * 64 + lane]);
            ax += v.x * w;
            ay += v.y * w;
        }

        ax = (ax > 0.0f) ? ax : expm1f(ax);
        ay = (ay > 0.0f) ? ay : expm1f(ay);
        obf[(size_t)c * 64 + lane] = pkbf(ax, ay);

        sx += ax; ssx += ax * ax;
        sy += ay; ssy += ay * ay;
    }

    // block reduce across the 4 waves (same lane = same column pair)
    __shared__ float4 sh[256];
    sh[tid] = make_float4(sx, sy, ssx, ssy);
    __syncthreads();
    if (tid < 64) {
        float4 a0 = sh[tid], a1 = sh[tid + 64], a2 = sh[tid + 128], a3 = sh[tid + 192];
        float4 t;
        t.x = a0.x + a1.x + a2.x + a3.x;
        t.y = a0.y + a1.y + a2.y + a3.y;
        t.z = a0.z + a1.z + a2.z + a3.z;
        t.w = a0.w + a1.w + a2.w + a3.w;
        *(float2*)&ps[(size_t)blockIdx.x * FEAT + 2 * tid]  = make_float2(t.x, t.y);
        *(float2*)&pss[(size_t)blockIdx.x * FEAT + 2 * tid] = make_float2(t.z, t.w);
    }
}

// ---------------------------------------------------------------------------
// Kernel H: reduce BN partials + last-block finalize (mu, rsqrt(var+eps))
// ---------------------------------------------------------------------------
__global__ __launch_bounds__(256) void k_bnreduce(const float* __restrict__ ps,
                                                  const float* __restrict__ pss,
                                                  float* __restrict__ bnsum, float* __restrict__ bnsq,
                                                  float n, unsigned* __restrict__ done) {
    const int col = threadIdx.x & 127;
    const int half = threadIdx.x >> 7;
    const float* src = half ? pss : ps;
    const int rows = AGG_BLOCKS / 64;
    const int r0 = blockIdx.x * rows;
    float acc = 0.0f;
    for (int r = r0; r < r0 + rows; r++) acc += src[(size_t)r * FEAT + col];
    atomicAdd(half ? &bnsq[col] : &bnsum[col], acc);
    __threadfence();
    __syncthreads();
    __shared__ unsigned lastv;
    if (threadIdx.x == 0) lastv = atomicAdd(done, 1u);
    __syncthreads();
    if (lastv == 63) {
        __threadfence();
        if (threadIdx.x < FEAT) {
            float su = atomicAdd(&bnsum[threadIdx.x], 0.0f);
            float sq = atomicAdd(&bnsq[threadIdx.x], 0.0f);
            float mu = su / n;
            float var = sq / n - mu * mu;
            if (var < 0.0f) var = 0.0f;
            bnsum[threadIdx.x] = mu;
            bnsq[threadIdx.x] = rsqrtf(var + 1e-5f);
        }
    }
}

// ---------------------------------------------------------------------------
// Kernel J: BN apply + LayerNorm; reads bf16x2 obf, writes fp32 out.
// ---------------------------------------------------------------------------
__global__ __launch_bounds__(256) void k_bn_ln(const unsigned* __restrict__ obf,
                                               float* __restrict__ out, const float* __restrict__ mu,
                                               const float* __restrict__ rsig,
                                               const float* __restrict__ bng, const float* __restrict__ bnb,
                                               const float* __restrict__ lng, const float* __restrict__ lnb,
                                               int n) {
    int wave = (blockIdx.x * 256 + threadIdx.x) >> 6;
    int lane = threadIdx.x & 63;
    if (wave >= n) return;
    int j0 = lane * 2;
    float2 v = upbf(obf[(size_t)wave * 64 + lane]);
    float t0 = (v.x - mu[j0])     * rsig[j0]     * bng[j0]     + bnb[j0];
    float t1 = (v.y - mu[j0 + 1]) * rsig[j0 + 1] * bng[j0 + 1] + bnb[j0 + 1];
    float s = t0 + t1;
    float ss = t0 * t0 + t1 * t1;
#pragma unroll
    for (int o = 32; o; o >>= 1) {
        s  += __shfl_xor(s, o);
        ss += __shfl_xor(ss, o);
    }
    float m = s * (1.0f / FEAT);
    float var = ss * (1.0f / FEAT) - m * m;
    float r = rsqrtf(var + 1e-5f);
    float o0 = (t0 - m) * r * lng[j0]     + lnb[j0];
    float o1 = (t1 - m) * r * lng[j0 + 1] + lnb[j0 + 1];
    *(float2*)&out[(size_t)wave * FEAT + j0] = make_float2(o0, o1);
}

// ---------------------------------------------------------------------------
extern "C" void kernel_launch(void* const* d_in, const int* in_sizes, int n_in,
                              void* d_out, int out_size, void* d_ws, size_t ws_size,
                              hipStream_t stream) {
    const float* x   = (const float*)d_in[0];
    const int*   ei  = (const int*)  d_in[1];
    const float* ew  = (const float*)d_in[2];
    const float* W   = (const float*)d_in[3];
    const float* b   = (const float*)d_in[4];
    const float* bng = (const float*)d_in[5];
    const float* bnb = (const float*)d_in[6];
    const float* lng = (const float*)d_in[7];
    const float* lnb = (const float*)d_in[8];

    const int N = in_sizes[0] / FEAT;     // 50000
    const int E = in_sizes[2];            // 800000

    const int nbuk = (N + NPB - 1) / NPB;                 // 196
    const int cap  = (((E / nbuk) * 5) / 4 + 127) & ~63;  // ~5184
    const int nblkA = (E + EPBA - 1) / EPBA;              // 196

    float* out = (float*)d_out;

    // workspace (16B-aligned; hb overlays buk — disjoint lifetimes)
    unsigned*           hb    = (unsigned*)d_ws;                       // N*64 u32 = 12.8MB
    unsigned long long* buk   = (unsigned long long*)d_ws;             // overlay
    size_t hbWords = (size_t)N * 64;
    size_t bukWords2 = ((size_t)nbuk * cap * 2);
    size_t reg1 = hbWords > bukWords2 ? hbWords : bukWords2;
    int2*               rec   = (int2*)(hb + reg1);                    // E int2
    unsigned*           obf   = (unsigned*)(rec + E);                  // N*64 u32
    float*              dinv  = (float*)(obf + (size_t)N * 64);        // N f32
    int*                start = (int*)(dinv + N);                      // N+4 i32
    unsigned*           gcur  = (unsigned*)(start + N + 4);            // 256 u32
    unsigned*           done  = gcur + 256;                            // 4 u32
    float*              bnsum = (float*)(done + 4);
    float*              bnsq  = bnsum + FEAT;
    float*              ps    = bnsq + FEAT;                           // AGG_BLOCKS*128
    float*              pss   = ps + (size_t)AGG_BLOCKS * FEAT;        // AGG_BLOCKS*128

    // A: init
    k_init2<<<1, 256, 0, stream>>>(gcur, bnsum, bnsq, start, done, nbuk, cap, N, E);
    // B: bucket-partition edges
    k_bucket<<<nblkA, 256, 0, stream>>>(ei, ew, buk, gcur, E, nbuk, cap);
    // C: per-bucket CSR build (writes dinv)
    k_csr<<<nbuk, 256, 0, stream>>>(buk, gcur, rec, start, dinv, N, nbuk, cap);
    // F: hbs = (x @ W)*dinv (MFMA, bf16 out)
    k_gemm_mfma<<<(N + 127) / 128, 256, 0, stream>>>(x, W, dinv, (unsigned short*)hb, N);
    // G: aggregate + self-loop + bias + ELU + fused BN partials -> obf (bf16)
    k_agg<<<AGG_BLOCKS, 256, 0, stream>>>(start, rec, dinv, hb, b, obf, ps, pss, N);
    // H: reduce BN partials + fused finalize
    k_bnreduce<<<64, 256, 0, stream>>>(ps, pss, bnsum, bnsq, (float)N, done);
    // J: BN apply + LayerNorm (obf -> fp32 out)
    k_bn_ln<<<(N + 3) / 4, 256, 0, stream>>>(obf, out, bnsum, bnsq, bng, bnb, lng, lnb, N);
}

// Round 15
// 109.043 us; speedup vs baseline: 1.0981x; 1.0981x over previous
//
#include <hip/hip_runtime.h>
#include <math.h>

#define FEAT 128
#define FXS 16777216.0f          // 2^24 fixed-point scale for edge weights
#define FXI (1.0f / 16777216.0f)
#define AGG_BLOCKS 2048          // k_agg grid; also BN partial rows
#define NPB 256                  // nodes per bucket (bucket = c >> 8)
#define EPBA 4096                // edges per phase-A block

typedef __attribute__((ext_vector_type(8)))  short short8;
typedef __attribute__((ext_vector_type(16))) float f32x16;

// bf16 helpers (bit-level, RNE pack / exact unpack)
__device__ inline unsigned pkbf(float a, float b) {
    unsigned ua = __float_as_uint(a), ub = __float_as_uint(b);
    ua += 0x7fffu + ((ua >> 16) & 1u);
    ub += 0x7fffu + ((ub >> 16) & 1u);
    return (ua >> 16) | (ub & 0xffff0000u);
}
__device__ inline unsigned short bf16of(float a) {
    unsigned ua = __float_as_uint(a);
    ua += 0x7fffu + ((ua >> 16) & 1u);
    return (unsigned short)(ua >> 16);
}
__device__ inline float2 upbf(unsigned v) {
    return make_float2(__uint_as_float(v << 16), __uint_as_float(v & 0xffff0000u));
}

// ---------------------------------------------------------------------------
// Kernel A: init — bucket cursors, BN sums, done counter, start[n]=E
// ---------------------------------------------------------------------------
__global__ __launch_bounds__(256) void k_init2(unsigned* __restrict__ gcur,
                                               float* __restrict__ bnsum, float* __restrict__ bnsq,
                                               int* __restrict__ start, unsigned* __restrict__ done,
                                               int nbuk, int cap, int n, int E) {
    int i = threadIdx.x;
    if (i < nbuk) gcur[i] = (unsigned)(i * cap);
    if (i < FEAT) { bnsum[i] = 0.0f; bnsq[i] = 0.0f; }
    if (i == 0) { start[n] = E; *done = 0u; }
}

// ---------------------------------------------------------------------------
// Kernel B (phase A): bucket-partition edges.
// Record: u64 = r | c<<17 | fx24(ew)<<34
// ---------------------------------------------------------------------------
__global__ __launch_bounds__(256) void k_bucket(const int* __restrict__ ei, const float* __restrict__ ew,
                                                unsigned long long* __restrict__ buk,
                                                unsigned* __restrict__ gcur,
                                                int E, int nbuk, int cap) {
    __shared__ unsigned bcnt[256];
    __shared__ unsigned bbase[256];
    const int tid = threadIdx.x;
    for (int i = tid; i < nbuk; i += 256) bcnt[i] = 0;
    __syncthreads();
    const int e0 = blockIdx.x * EPBA;
    const int e1 = (e0 + EPBA < E) ? e0 + EPBA : E;
    for (int e = e0 + tid; e < e1; e += 256) {
        int c = ei[E + e];
        atomicAdd(&bcnt[c >> 8], 1u);
    }
    __syncthreads();
    for (int i = tid; i < nbuk; i += 256) {
        unsigned nn = bcnt[i];
        bbase[i] = nn ? atomicAdd(&gcur[i], nn) : 0u;
        bcnt[i] = 0;   // reuse as local cursor
    }
    __syncthreads();
    for (int e = e0 + tid; e < e1; e += 256) {
        int r = ei[e];
        int c = ei[E + e];
        unsigned fx = (unsigned)(ew[e] * FXS + 0.5f);
        int b = c >> 8;
        unsigned slot = bbase[b] + atomicAdd(&bcnt[b], 1u);
        buk[slot] = (unsigned long long)(unsigned)r
                  | ((unsigned long long)(unsigned)c << 17)
                  | ((unsigned long long)fx << 34);
    }
}

// ---------------------------------------------------------------------------
// Kernel C (phase B): per-bucket CSR build. One block per bucket.
// ---------------------------------------------------------------------------
__global__ __launch_bounds__(256) void k_csr(const unsigned long long* __restrict__ buk,
                                             const unsigned* __restrict__ gcur,
                                             int2* __restrict__ rec, int* __restrict__ start,
                                             float* __restrict__ dinv,
                                             int n, int nbuk, int cap) {
    __shared__ unsigned long long cd[NPB];
    __shared__ unsigned curL[NPB];
    __shared__ unsigned sizeL[256];
    __shared__ unsigned wt[4];
    const int b = blockIdx.x;
    const int tid = threadIdx.x;
    const int lane = tid & 63;
    const int wv = tid >> 6;

    unsigned sz = (tid < nbuk) ? (gcur[tid] - (unsigned)(tid * cap)) : 0u;
    {
        unsigned s = sz;
#pragma unroll
        for (int o = 1; o < 64; o <<= 1) {
            unsigned u = __shfl_up((int)s, o);
            if (lane >= o) s += u;
        }
        if (lane == 63) wt[wv] = s;
        __syncthreads();
        unsigned woff = 0;
#pragma unroll
        for (int w = 0; w < 4; w++) if (w < wv) woff += wt[w];
        sizeL[tid] = woff + s - sz;   // exclusive
        __syncthreads();
    }
    const unsigned bukStartG = sizeL[b];
    const unsigned mySize = gcur[b] - (unsigned)(b * cap);
    const unsigned base = (unsigned)b * (unsigned)cap;

    cd[tid] = 0ULL;
    __syncthreads();

    for (unsigned i = tid; i < mySize; i += 256) {
        unsigned long long v = buk[base + i];
        unsigned ci = ((unsigned)(v >> 17)) & 255u;
        atomicAdd(&cd[ci], (1ULL << 40) | (v >> 34));
    }
    __syncthreads();

    {
        unsigned long long v = cd[tid];
        unsigned cnt = (unsigned)(v >> 40);
        float deg = 1.0f + (float)(v & ((1ULL << 40) - 1ULL)) * FXI;
        unsigned s = cnt;
#pragma unroll
        for (int o = 1; o < 64; o <<= 1) {
            unsigned u = __shfl_up((int)s, o);
            if (lane >= o) s += u;
        }
        __syncthreads();          // wt reuse
        if (lane == 63) wt[wv] = s;
        __syncthreads();
        unsigned woff = 0;
#pragma unroll
        for (int w = 0; w < 4; w++) if (w < wv) woff += wt[w];
        unsigned excl = woff + s - cnt;
        curL[tid] = bukStartG + excl;
        int gc = b * NPB + tid;
        if (gc < n) {
            start[gc] = (int)(bukStartG + excl);
            dinv[gc] = rsqrtf(deg);
        }
    }
    __syncthreads();

    for (unsigned i = tid; i < mySize; i += 256) {
        unsigned long long v = buk[base + i];
        unsigned r = (unsigned)v & 0x1FFFFu;
        unsigned ci = ((unsigned)(v >> 17)) & 255u;
        float w = (float)(v >> 34) * FXI;
        unsigned pos = atomicAdd(&curL[ci], 1u);
        rec[pos] = make_int2((int)r, __float_as_int(w));
    }
}

// ---------------------------------------------------------------------------
// Kernel F: hbs = (x @ W) * dinv[row]  via MFMA 32x32x16 bf16
// ---------------------------------------------------------------------------
__global__ __launch_bounds__(256) void k_gemm_mfma(const float* __restrict__ x,
                                                   const float* __restrict__ Wg,
                                                   const float* __restrict__ dinv,
                                                   unsigned short* __restrict__ hb, int nrows) {
    __shared__ unsigned wlds[4][8][64][4];   // 32 KB
    const int tid = threadIdx.x;

    for (int idx = tid; idx < 4 * 8 * 64; idx += 256) {
        int lane = idx & 63;
        int ks = (idx >> 6) & 7;
        int ct = idx >> 9;
        int krow = ks * 16 + 8 * (lane >> 5);
        int col = ct * 32 + (lane & 31);
        unsigned u0 = pkbf(Wg[(krow + 0) * FEAT + col], Wg[(krow + 1) * FEAT + col]);
        unsigned u1 = pkbf(Wg[(krow + 2) * FEAT + col], Wg[(krow + 3) * FEAT + col]);
        unsigned u2 = pkbf(Wg[(krow + 4) * FEAT + col], Wg[(krow + 5) * FEAT + col]);
        unsigned u3 = pkbf(Wg[(krow + 6) * FEAT + col], Wg[(krow + 7) * FEAT + col]);
        *(uint4*)&wlds[ct][ks][lane][0] = make_uint4(u0, u1, u2, u3);
    }
    __syncthreads();

    const int w = tid >> 6;
    const int lane = tid & 63;
    const int row = blockIdx.x * 128 + w * 32 + (lane & 31);
    const int rclamp = (row < nrows) ? row : 0;
    const float* xrow = x + (size_t)rclamp * FEAT + 8 * (lane >> 5);

    f32x16 acc0 = {0}, acc1 = {0}, acc2 = {0}, acc3 = {0};

#pragma unroll
    for (int ks = 0; ks < 8; ks++) {
        float4 f0 = *(const float4*)&xrow[ks * 16];
        float4 f1 = *(const float4*)&xrow[ks * 16 + 4];
        union { uint4 u; short8 s; } a;
        a.u = make_uint4(pkbf(f0.x, f0.y), pkbf(f0.z, f0.w), pkbf(f1.x, f1.y), pkbf(f1.z, f1.w));
        union { uint4 u; short8 s; } b0, b1, b2, b3;
        b0.u = *(const uint4*)&wlds[0][ks][lane][0];
        b1.u = *(const uint4*)&wlds[1][ks][lane][0];
        b2.u = *(const uint4*)&wlds[2][ks][lane][0];
        b3.u = *(const uint4*)&wlds[3][ks][lane][0];
        acc0 = __builtin_amdgcn_mfma_f32_32x32x16_bf16(a.s, b0.s, acc0, 0, 0, 0);
        acc1 = __builtin_amdgcn_mfma_f32_32x32x16_bf16(a.s, b1.s, acc1, 0, 0, 0);
        acc2 = __builtin_amdgcn_mfma_f32_32x32x16_bf16(a.s, b2.s, acc2, 0, 0, 0);
        acc3 = __builtin_amdgcn_mfma_f32_32x32x16_bf16(a.s, b3.s, acc3, 0, 0, 0);
    }

    const int rb = blockIdx.x * 128 + w * 32 + 4 * (lane >> 5);
    const int cb = lane & 31;
#pragma unroll
    for (int r = 0; r < 16; r++) {
        int rr = rb + (r & 3) + 8 * (r >> 2);
        if (rr < nrows) {
            float dv = dinv[rr];
            unsigned short* p = hb + (size_t)rr * FEAT + cb;
            p[0]  = bf16of(acc0[r] * dv);
            p[32] = bf16of(acc1[r] * dv);
            p[64] = bf16of(acc2[r] * dv);
            p[96] = bf16of(acc3[r] * dv);
        }
    }
}

// ---------------------------------------------------------------------------
// Kernel G: aggregate + fused BN partials (R9/R12 structure: 1 wave/node,
// 2 feats/lane, dword gathers, 8 edges in flight; bf16 obf out).
// rec pairs loaded as uint4 (2 edges per broadcast load).
// ---------------------------------------------------------------------------
__global__ __launch_bounds__(256) void k_agg(const int* __restrict__ start,
                                             const int2* __restrict__ rec, const float* __restrict__ dinv,
                                             const unsigned* __restrict__ hb, const float* __restrict__ b,
                                             unsigned* __restrict__ obf,
                                             float* __restrict__ ps, float* __restrict__ pss, int n) {
    const int tid = threadIdx.x;
    const int lane = tid & 63;
    const int wv = tid >> 6;
    const int j0 = lane * 2;
    const float bx = b[j0];
    const float by = b[j0 + 1];

    float sx = 0.0f, ssx = 0.0f, sy = 0.0f, ssy = 0.0f;

    for (int c = blockIdx.x * 4 + wv; c < n; c += AGG_BLOCKS * 4) {
        const int s0 = start[c];
        const int m = start[c + 1] - s0;
        const float dc = dinv[c];

        float2 hv = upbf(hb[(size_t)c * 64 + lane]);
        float ax = hv.x * dc + bx;
        float ay = hv.y * dc + by;

        int k = 0;
        for (; k + 7 < m; k += 8) {
            uint4 ra = *(const uint4*)&rec[s0 + k];
            uint4 rb2 = *(const uint4*)&rec[s0 + k + 2];
            uint4 rc = *(const uint4*)&rec[s0 + k + 4];
            uint4 rd = *(const uint4*)&rec[s0 + k + 6];
            unsigned g0 = hb[(size_t)ra.x  * 64 + lane];
            unsigned g1 = hb[(size_t)ra.z  * 64 + lane];
            unsigned g2 = hb[(size_t)rb2.x * 64 + lane];
            unsigned g3 = hb[(size_t)rb2.z * 64 + lane];
            unsigned g4 = hb[(size_t)rc.x  * 64 + lane];
            unsigned g5 = hb[(size_t)rc.z  * 64 + lane];
            unsigned g6 = hb[(size_t)rd.x  * 64 + lane];
            unsigned g7 = hb[(size_t)rd.z  * 64 + lane];
            float w0 = __uint_as_float(ra.y)  * dc;
            float w1 = __uint_as_float(ra.w)  * dc;
            float w2 = __uint_as_float(rb2.y) * dc;
            float w3 = __uint_as_float(rb2.w) * dc;
            float w4 = __uint_as_float(rc.y)  * dc;
            float w5 = __uint_as_float(rc.w)  * dc;
            float w6 = __uint_as_float(rd.y)  * dc;
            float w7 = __uint_as_float(rd.w)  * dc;
            float2 v0 = upbf(g0), v1 = upbf(g1), v2 = upbf(g2), v3 = upbf(g3);
            float2 v4 = upbf(g4), v5 = upbf(g5), v6 = upbf(g6), v7 = upbf(g7);
            ax += v0.x * w0 + v1.x * w1 + v2.x * w2 + v3.x * w3
                + v4.x * w4 + v5.x * w5 + v6.x * w6 + v7.x * w7;
            ay += v0.y * w0 + v1.y * w1 + v2.y * w2 + v3.y * w3
                + v4.y * w4 + v5.y * w5 + v6.y * w6 + v7.y * w7;
        }
        for (; k + 3 < m; k += 4) {
            uint4 ra = *(const uint4*)&rec[s0 + k];
            uint4 rb2 = *(const uint4*)&rec[s0 + k + 2];
            unsigned g0 = hb[(size_t)ra.x  * 64 + lane];
            unsigned g1 = hb[(size_t)ra.z  * 64 + lane];
            unsigned g2 = hb[(size_t)rb2.x * 64 + lane];
            unsigned g3 = hb[(size_t)rb2.z * 64 + lane];
            float w0 = __uint_as_float(ra.y)  * dc;
            float w1 = __uint_as_float(ra.w)  * dc;
            float w2 = __uint_as_float(rb2.y) * dc;
            float w3 = __uint_as_float(rb2.w) * dc;
            float2 v0 = upbf(g0), v1 = upbf(g1), v2 = upbf(g2), v3 = upbf(g3);
            ax += v0.x * w0 + v1.x * w1 + v2.x * w2 + v3.x * w3;
            ay += v0.y * w0 + v1.y * w1 + v2.y * w2 + v3.y * w3;
        }
        for (; k < m; k++) {
            int2 r0 = rec[s0 + k];
            float w = __int_as_float(r0.y) * dc;
            float2 v = upbf(hb[(size_t)r0.x * 64 + lane]);
            ax += v.x * w;
            ay += v.y * w;
        }

        ax = (ax > 0.0f) ? ax : expm1f(ax);
        ay = (ay > 0.0f) ? ay : expm1f(ay);
        obf[(size_t)c * 64 + lane] = pkbf(ax, ay);

        sx += ax; ssx += ax * ax;
        sy += ay; ssy += ay * ay;
    }

    // block reduce across the 4 waves (same lane = same column pair)
    __shared__ float4 sh[256];
    sh[tid] = make_float4(sx, sy, ssx, ssy);
    __syncthreads();
    if (tid < 64) {
        float4 a0 = sh[tid], a1 = sh[tid + 64], a2 = sh[tid + 128], a3 = sh[tid + 192];
        float4 t;
        t.x = a0.x + a1.x + a2.x + a3.x;
        t.y = a0.y + a1.y + a2.y + a3.y;
        t.z = a0.z + a1.z + a2.z + a3.z;
        t.w = a0.w + a1.w + a2.w + a3.w;
        *(float2*)&ps[(size_t)blockIdx.x * FEAT + 2 * tid]  = make_float2(t.x, t.y);
        *(float2*)&pss[(size_t)blockIdx.x * FEAT + 2 * tid] = make_float2(t.z, t.w);
    }
}

// ---------------------------------------------------------------------------
// Kernel H: reduce BN partials + last-block finalize (mu, rsqrt(var+eps))
// ---------------------------------------------------------------------------
__global__ __launch_bounds__(256) void k_bnreduce(const float* __restrict__ ps,
                                                  const float* __restrict__ pss,
                                                  float* __restrict__ bnsum, float* __restrict__ bnsq,
                                                  float n, unsigned* __restrict__ done) {
    const int col = threadIdx.x & 127;
    const int half = threadIdx.x >> 7;
    const float* src = half ? pss : ps;
    const int rows = AGG_BLOCKS / 64;
    const int r0 = blockIdx.x * rows;
    float acc = 0.0f;
    for (int r = r0; r < r0 + rows; r++) acc += src[(size_t)r * FEAT + col];
    atomicAdd(half ? &bnsq[col] : &bnsum[col], acc);
    __threadfence();
    __syncthreads();
    __shared__ unsigned lastv;
    if (threadIdx.x == 0) lastv = atomicAdd(done, 1u);
    __syncthreads();
    if (lastv == 63) {
        __threadfence();
        if (threadIdx.x < FEAT) {
            float su = atomicAdd(&bnsum[threadIdx.x], 0.0f);
            float sq = atomicAdd(&bnsq[threadIdx.x], 0.0f);
            float mu = su / n;
            float var = sq / n - mu * mu;
            if (var < 0.0f) var = 0.0f;
            bnsum[threadIdx.x] = mu;
            bnsq[threadIdx.x] = rsqrtf(var + 1e-5f);
        }
    }
}

// ---------------------------------------------------------------------------
// Kernel J: BN apply + LayerNorm; reads bf16x2 obf, writes fp32 out.
// ---------------------------------------------------------------------------
__global__ __launch_bounds__(256) void k_bn_ln(const unsigned* __restrict__ obf,
                                               float* __restrict__ out, const float* __restrict__ mu,
                                               const float* __restrict__ rsig,
                                               const float* __restrict__ bng, const float* __restrict__ bnb,
                                               const float* __restrict__ lng, const float* __restrict__ lnb,
                                               int n) {
    int wave = (blockIdx.x * 256 + threadIdx.x) >> 6;
    int lane = threadIdx.x & 63;
    if (wave >= n) return;
    int j0 = lane * 2;
    float2 v = upbf(obf[(size_t)wave * 64 + lane]);
    float t0 = (v.x - mu[j0])     * rsig[j0]     * bng[j0]     + bnb[j0];
    float t1 = (v.y - mu[j0 + 1]) * rsig[j0 + 1] * bng[j0 + 1] + bnb[j0 + 1];
    float s = t0 + t1;
    float ss = t0 * t0 + t1 * t1;
#pragma unroll
    for (int o = 32; o; o >>= 1) {
        s  += __shfl_xor(s, o);
        ss += __shfl_xor(ss, o);
    }
    float m = s * (1.0f / FEAT);
    float var = ss * (1.0f / FEAT) - m * m;
    float r = rsqrtf(var + 1e-5f);
    float o0 = (t0 - m) * r * lng[j0]     + lnb[j0];
    float o1 = (t1 - m) * r * lng[j0 + 1] + lnb[j0 + 1];
    *(float2*)&out[(size_t)wave * FEAT + j0] = make_float2(o0, o1);
}

// ---------------------------------------------------------------------------
extern "C" void kernel_launch(void* const* d_in, const int* in_sizes, int n_in,
                              void* d_out, int out_size, void* d_ws, size_t ws_size,
                              hipStream_t stream) {
    const float* x   = (const float*)d_in[0];
    const int*   ei  = (const int*)  d_in[1];
    const float* ew  = (const float*)d_in[2];
    const float* W   = (const float*)d_in[3];
    const float* b   = (const float*)d_in[4];
    const float* bng = (const float*)d_in[5];
    const float* bnb = (const float*)d_in[6];
    const float* lng = (const float*)d_in[7];
    const float* lnb = (const float*)d_in[8];

    const int N = in_sizes[0] / FEAT;     // 50000
    const int E = in_sizes[2];            // 800000

    const int nbuk = (N + NPB - 1) / NPB;                 // 196
    const int cap  = (((E / nbuk) * 5) / 4 + 127) & ~63;  // ~5184
    const int nblkA = (E + EPBA - 1) / EPBA;              // 196

    float* out = (float*)d_out;

    // workspace (16B-aligned; hb overlays buk — disjoint lifetimes)
    unsigned*           hb    = (unsigned*)d_ws;                       // N*64 u32 = 12.8MB
    unsigned long long* buk   = (unsigned long long*)d_ws;             // overlay
    size_t hbWords = (size_t)N * 64;
    size_t bukWords2 = ((size_t)nbuk * cap * 2);
    size_t reg1 = hbWords > bukWords2 ? hbWords : bukWords2;
    int2*               rec   = (int2*)(hb + reg1);                    // E int2
    unsigned*           obf   = (unsigned*)(rec + E);                  // N*64 u32
    float*              dinv  = (float*)(obf + (size_t)N * 64);        // N f32
    int*                start = (int*)(dinv + N);                      // N+4 i32
    unsigned*           gcur  = (unsigned*)(start + N + 4);            // 256 u32
    unsigned*           done  = gcur + 256;                            // 4 u32
    float*              bnsum = (float*)(done + 4);
    float*              bnsq  = bnsum + FEAT;
    float*              ps    = bnsq + FEAT;                           // AGG_BLOCKS*128
    float*              pss   = ps + (size_t)AGG_BLOCKS * FEAT;        // AGG_BLOCKS*128

    // A: init
    k_init2<<<1, 256, 0, stream>>>(gcur, bnsum, bnsq, start, done, nbuk, cap, N, E);
    // B: bucket-partition edges
    k_bucket<<<nblkA, 256, 0, stream>>>(ei, ew, buk, gcur, E, nbuk, cap);
    // C: per-bucket CSR build (writes dinv)
    k_csr<<<nbuk, 256, 0, stream>>>(buk, gcur, rec, start, dinv, N, nbuk, cap);
    // F: hbs = (x @ W)*dinv (MFMA, bf16 out)
    k_gemm_mfma<<<(N + 127) / 128, 256, 0, stream>>>(x, W, dinv, (unsigned short*)hb, N);
    // G: aggregate + self-loop + bias + ELU + fused BN partials -> obf (bf16)
    k_agg<<<AGG_BLOCKS, 256, 0, stream>>>(start, rec, dinv, hb, b, obf, ps, pss, N);
    // H: reduce BN partials + fused finalize
    k_bnreduce<<<64, 256, 0, stream>>>(ps, pss, bnsum, bnsq, (float)N, done);
    // J: BN apply + LayerNorm (obf -> fp32 out)
    k_bn_ln<<<(N + 3) / 4, 256, 0, stream>>>(obf, out, bnsum, bnsq, bng, bnb, lng, lnb, N);
}